// Round 3
// baseline (457.514 us; speedup 1.0000x reference)
//
#include <hip/hip_runtime.h>
#include <hip/hip_bf16.h>
#include <stdint.h>

// MoE gate: logits = r @ W^T + b ; soft = softmax(logits) ; hard = top8-renorm
// r: (32768, 2048) fp32, W: (64, 2048) fp32, b: (64,) fp32
// d_out: [hard (32768*64) | soft (32768*64)] fp32
//
// Precision: exact bf16^3 split of both operands, 6 MFMA terms in 3 scale-
// class accumulators (verified: absmax 0.00195 vs 0.01625 thr). NUMERICS
// UNCHANGED this round (top-k tie sensitivity: logit perturbations can flip
// rank-8/9 selections, so the 3x3 split stays).
//
// Round-6 theory: round-5 was a latency CHAIN — issue order A(k+1),B(k),
// MFMA(k) means waiting on B(k) (youngest loads) drains vmcnt to 0 and kills
// the A prefetch too; every k-step pays a bare L2/HBM round trip. Fix:
// explicit 2-deep register double-buffer for BOTH A and B, hand-unrolled x2.
// Steady state: wait vmcnt(14) [k's loads] -> MFMA(k) -> issue B(k+2),A(k+2);
// 14 loads always in flight, prefetch distance 2 k-steps (~600-900 cy) covers
// L2 (~250) and HBM (~900). Pays ~190 VGPR -> 2 waves/SIMD; fine, because
// once pipelined the limiter is L2 B-traffic (~30 us) + A stream (~25-43 us),
// not TLP.

#define D_DIM 2048
#define E_DIM 64
#define B_DIM 32768
#define TOPK 8
#define NK 16   // k-steps per quarter (32 k each)

typedef __bf16 bf16x8 __attribute__((ext_vector_type(8)));
typedef float f32x4 __attribute__((ext_vector_type(4)));

// ---- prep: W fp32 -> per-kstep fragment image ----
// P[ks][split][2048 bf16] = 12 KB per kstep. Element (s, u*8+j) = split_s of
// W[e = u>>2][ks*32 + (u&3)*8 + j]. Fragment (s,n) of kstep ks occupies the
// contiguous aligned 1 KB at P + ks*6144 + s*2048 + n*512; within it, lane
// (quad,lrow) reads 16 B at quad*16 + lrow*64 -> expert n*16+lrow, k-chunk
// quad*8 .. +8, matching the mfma_f32_16x16x32_bf16 B-fragment layout.
__global__ __launch_bounds__(256) void w_prep(const float* __restrict__ W,
                                              __bf16* __restrict__ P) {
    const int K = blockIdx.x;    // kstep 0..63
    const int u = threadIdx.x;   // slot 0..255
    const float* src = W + (size_t)(u >> 2) * D_DIM + K * 32 + (u & 3) * 8;
    __bf16* dst = P + (size_t)K * 6144 + u * 8;
    bf16x8 o1, o2, o3;
    #pragma unroll
    for (int j = 0; j < 8; ++j) {
        float x  = src[j];
        __bf16 h1 = (__bf16)x;
        float r1 = x - (float)h1;          // exact
        __bf16 h2 = (__bf16)r1;
        float r2 = r1 - (float)h2;         // exact
        o1[j] = h1; o2[j] = h2; o3[j] = (__bf16)r2;
    }
    *(bf16x8*)(dst)        = o1;
    *(bf16x8*)(dst + 2048) = o2;
    *(bf16x8*)(dst + 4096) = o3;
}

// ---- main: 6-term split GEMM + fused softmax/top-8, pipelined K-loop ----
// Block = 256 thr = 4 waves; wave wv = K-quarter, owns 16 rows x 64 experts
// x 512 k. Grid = 2048 blocks (16 rows each). No K-loop barriers.
__global__ __launch_bounds__(256, 2) void moe_gate(const float* __restrict__ r,
                                                   const __bf16* __restrict__ P,
                                                   const float* __restrict__ bias,
                                                   float* __restrict__ out) {
    __shared__ float lg[4][16][E_DIM + 1];   // per-quarter partials, 16.6 KB

    const int t    = threadIdx.x;
    const int wv   = t >> 6;     // K quarter
    const int lane = t & 63;
    const int lrow = lane & 15;
    const int quad = lane >> 4;
    const int row0 = blockIdx.x * 16;

    // B source: this quarter's k-steps, this lane's 16 B within each fragment
    const __bf16* Pq = P + (size_t)wv * NK * 6144 + quad * 8 + lrow * 32;
    // A source: row lrow, this quarter's k range, quad's 8-float chunk
    const float* ra = r + (size_t)(row0 + lrow) * D_DIM + wv * 512 + quad * 8;

    f32x4 accM[4] = {};  // h1*g1              (~1)
    f32x4 accD[4] = {};  // h1*g2 + h2*g1      (~2^-8)
    f32x4 accL[4] = {};  // h1*g3+h2*g2+h3*g1  (~2^-16)

    // double-buffered operand registers (named sets -> static indexing only)
    bf16x8 B0[3][4], B1[3][4];
    float4 p00, p01, p10, p11;

#define LOADB(Bd, kk) do {                                                  \
        const __bf16* bb_ = Pq + (size_t)(kk) * 6144;                       \
        _Pragma("unroll")                                                   \
        for (int s_ = 0; s_ < 3; ++s_)                                      \
            _Pragma("unroll")                                               \
            for (int n_ = 0; n_ < 4; ++n_)                                  \
                Bd[s_][n_] = *(const bf16x8*)(bb_ + s_ * 2048 + n_ * 512);  \
    } while (0)

#define LOADA(pa_, pb_, kk) do {                                            \
        pa_ = *(const float4*)(ra + (kk) * 32);                             \
        pb_ = *(const float4*)(ra + (kk) * 32 + 4);                         \
    } while (0)

#define COMPUTE(Bd, pa_, pb_) do {                                          \
        float av_[8] = {pa_.x, pa_.y, pa_.z, pa_.w,                         \
                        pb_.x, pb_.y, pb_.z, pb_.w};                        \
        bf16x8 A1_, A2_, A3_;                                               \
        _Pragma("unroll")                                                   \
        for (int j_ = 0; j_ < 8; ++j_) {                                    \
            float x_  = av_[j_];                                            \
            __bf16 h1_ = (__bf16)x_;                                        \
            float r1_ = x_ - (float)h1_;                                    \
            __bf16 h2_ = (__bf16)r1_;                                       \
            float r2_ = r1_ - (float)h2_;                                   \
            A1_[j_] = h1_; A2_[j_] = h2_; A3_[j_] = (__bf16)r2_;            \
        }                                                                   \
        _Pragma("unroll")                                                   \
        for (int n_ = 0; n_ < 4; ++n_) {                                    \
            accM[n_] = __builtin_amdgcn_mfma_f32_16x16x32_bf16(A1_, Bd[0][n_], accM[n_], 0, 0, 0); \
            accD[n_] = __builtin_amdgcn_mfma_f32_16x16x32_bf16(A1_, Bd[1][n_], accD[n_], 0, 0, 0); \
            accD[n_] = __builtin_amdgcn_mfma_f32_16x16x32_bf16(A2_, Bd[0][n_], accD[n_], 0, 0, 0); \
            accL[n_] = __builtin_amdgcn_mfma_f32_16x16x32_bf16(A1_, Bd[2][n_], accL[n_], 0, 0, 0); \
            accL[n_] = __builtin_amdgcn_mfma_f32_16x16x32_bf16(A2_, Bd[1][n_], accL[n_], 0, 0, 0); \
            accL[n_] = __builtin_amdgcn_mfma_f32_16x16x32_bf16(A3_, Bd[0][n_], accL[n_], 0, 0, 0); \
        }                                                                   \
    } while (0)

    // prologue: fill both pipeline slots (28 loads in flight)
    LOADB(B0, 0); LOADA(p00, p01, 0);
    LOADB(B1, 1); LOADA(p10, p11, 1);

    #pragma unroll
    for (int ks = 0; ks < NK; ks += 2) {
        // clamped next-indices: tail iterations issue harmless redundant
        // reloads of already-valid addresses (keeps schedule uniform)
        const int k2 = (ks + 2 < NK) ? ks + 2 : ks;
        const int k3 = (ks + 3 < NK) ? ks + 3 : ks + 1;

        COMPUTE(B0, p00, p01);          // waits vmcnt(14): slot-1 stays in flight
        LOADB(B0, k2); LOADA(p00, p01, k2);

        COMPUTE(B1, p10, p11);          // waits vmcnt(14): slot-0 stays in flight
        LOADB(B1, k3); LOADA(p10, p11, k3);
    }

#undef LOADB
#undef LOADA
#undef COMPUTE

    // C/D layout: col = lane&15, row = quad*4 + reg. Combine small-first,
    // one partial per K-quarter.
    #pragma unroll
    for (int n = 0; n < 4; ++n) {
        int col = n * 16 + lrow;
        #pragma unroll
        for (int i = 0; i < 4; ++i)
            lg[wv][quad * 4 + i][col] = accM[n][i] + (accD[n][i] + accL[n][i]);
    }
    __syncthreads();   // the ONLY block-wide barrier

    // quarter-reduce + softmax + top-8; wave per row, lane = expert. T == 1.
    const float bcol = bias[lane];
    for (int rr = wv; rr < 16; rr += 4) {
        float logit = ((lg[0][rr][lane] + lg[1][rr][lane]) +
                       (lg[2][rr][lane] + lg[3][rr][lane])) + bcol;
        float mx = logit;
        #pragma unroll
        for (int s = 32; s >= 1; s >>= 1) mx = fmaxf(mx, __shfl_xor(mx, s));
        float ex = expf(logit - mx);
        float sm = ex;
        #pragma unroll
        for (int s = 32; s >= 1; s >>= 1) sm += __shfl_xor(sm, s);
        float soft = ex / sm;

        // top-8 on soft (monotone in logit); lowest-index tie-break = lax.top_k
        bool  sel    = false;
        float topsum = 0.0f;
        #pragma unroll
        for (int it = 0; it < TOPK; ++it) {
            float cand = sel ? -1.0f : soft;  // soft > 0 always
            float cm = cand;
            #pragma unroll
            for (int s = 32; s >= 1; s >>= 1) cm = fmaxf(cm, __shfl_xor(cm, s));
            unsigned long long ball = __ballot(cand == cm);
            int leader = __ffsll(ball) - 1;
            if (lane == leader) sel = true;
            topsum += cm;
        }
        float hard = sel ? soft / (topsum + 1e-9f) : 0.0f;

        size_t orow = (size_t)(row0 + rr) * E_DIM + lane;
        out[orow] = hard;
        out[(size_t)B_DIM * E_DIM + orow] = soft;
    }
}

extern "C" void kernel_launch(void* const* d_in, const int* in_sizes, int n_in,
                              void* d_out, int out_size, void* d_ws, size_t ws_size,
                              hipStream_t stream) {
    const float* r = (const float*)d_in[0];
    const float* W = (const float*)d_in[1];
    const float* b = (const float*)d_in[2];
    float* out = (float*)d_out;
    __bf16* P = (__bf16*)d_ws;   // 64 ksteps * 12 KB = 768 KB of ws

    w_prep<<<64, 256, 0, stream>>>(W, P);
    moe_gate<<<2048, 256, 0, stream>>>(r, P, b, out);
}

// Round 4
// 402.764 us; speedup vs baseline: 1.1359x; 1.1359x over previous
//
#include <hip/hip_runtime.h>
#include <hip/hip_bf16.h>
#include <stdint.h>

// MoE gate: logits = r @ W^T + b ; soft = softmax(logits) ; hard = top8-renorm
// r: (32768, 2048) fp32, W: (64, 2048) fp32, b: (64,) fp32
// d_out: [hard (32768*64) | soft (32768*64)] fp32
//
// Precision: exact bf16^3 split of both operands, all 6 MFMA terms kept.
// D and L scale classes now share one accumulator (terms differ by 2^-8;
// fp32 accumulate error from merging ~2^-27 absolute — invisible vs the
// verified 0.00195 absmax, 0.01625 thr).
//
// Round-7 theory: round-6's reg-dbuf was DEFEATED by the compiler (VGPR=60
// proves loads were sunk to point-of-use; ~500cy serial round-trip per load
// group). Fix: (a) 32 rows/wave so 48 MFMA + 2 A-splits (~700cy) sit behind
// each 16-load group; (b) sched_barrier(0) fences after each prefetch-issue
// group pin the software pipeline (WAR deps stop hoisting; fences stop
// sinking). Steady state: counted vmcnt(16) wait -> compute(k) -> issue
// k+2 -> fence -> compute(k+1). Verification signal: VGPR must be ~210+.

#define D_DIM 2048
#define E_DIM 64
#define B_DIM 32768
#define TOPK 8
#define NK 16   // k-steps per quarter (32 k each)

typedef __bf16 bf16x8 __attribute__((ext_vector_type(8)));
typedef float f32x4 __attribute__((ext_vector_type(4)));

// ---- prep: W fp32 -> per-kstep fragment image ----
// P[ks][split][2048 bf16] = 12 KB per kstep. Element (s, u*8+j) = split_s of
// W[e = u>>2][ks*32 + (u&3)*8 + j]. Fragment (s,n) of kstep ks is the
// contiguous aligned 1 KB at P + ks*6144 + s*2048 + n*512; lane (quad,lrow)
// reads 16 B at quad*16 + lrow*64 -> expert n*16+lrow, k-chunk quad*8..+8,
// matching the mfma_f32_16x16x32_bf16 B-fragment layout (layout verified by
// rounds 5-6 passing).
__global__ __launch_bounds__(256) void w_prep(const float* __restrict__ W,
                                              __bf16* __restrict__ P) {
    const int K = blockIdx.x;    // kstep 0..63
    const int u = threadIdx.x;   // slot 0..255
    const float* src = W + (size_t)(u >> 2) * D_DIM + K * 32 + (u & 3) * 8;
    __bf16* dst = P + (size_t)K * 6144 + u * 8;
    bf16x8 o1, o2, o3;
    #pragma unroll
    for (int j = 0; j < 8; ++j) {
        float x  = src[j];
        __bf16 h1 = (__bf16)x;
        float r1 = x - (float)h1;          // exact
        __bf16 h2 = (__bf16)r1;
        float r2 = r1 - (float)h2;         // exact
        o1[j] = h1; o2[j] = h2; o3[j] = (__bf16)r2;
    }
    *(bf16x8*)(dst)        = o1;
    *(bf16x8*)(dst + 2048) = o2;
    *(bf16x8*)(dst + 4096) = o3;
}

// ---- main: 6-term split GEMM + fused softmax/top-8, pinned pipeline ----
// Block = 256 thr = 4 waves; wave wv = K-quarter, owns 32 rows x 64 experts
// x 512 k. Grid = 1024 blocks (32 rows each). No K-loop barriers.
__global__ __launch_bounds__(256, 2) void moe_gate(const float* __restrict__ r,
                                                   const __bf16* __restrict__ P,
                                                   const float* __restrict__ bias,
                                                   float* __restrict__ out) {
    __shared__ float lg[4][32][E_DIM + 4];   // per-quarter partials, 34.8 KB

    const int t    = threadIdx.x;
    const int wv   = t >> 6;     // K quarter
    const int lane = t & 63;
    const int lrow = lane & 15;
    const int quad = lane >> 4;
    const int row0 = blockIdx.x * 32;

    // B source: this quarter's k-steps, this lane's 16 B within each fragment
    const __bf16* Pq = P + (size_t)wv * NK * 6144 + quad * 8 + lrow * 32;
    // A sources: row-tile 0 and 1, this quarter's k range, quad's 8-float chunk
    const float* ra0 = r + (size_t)(row0 + lrow) * D_DIM + wv * 512 + quad * 8;
    const float* ra1 = ra0 + (size_t)16 * D_DIM;

    f32x4 accM[2][4]  = {};  // h1*g1 per (row-tile, expert-frag)   (~1)
    f32x4 accDL[2][4] = {};  // all 5 cross terms                   (~2^-8)

    // double-buffered operand registers (named sets, static indexing only)
    bf16x8 B0[3][4], B1[3][4];       // 96 VGPR
    float4 A0[2][2], A1[2][2];       // 32 VGPR

#define LOADB(Bd, kk) do {                                                  \
        const __bf16* bb_ = Pq + (size_t)(kk) * 6144;                       \
        _Pragma("unroll")                                                   \
        for (int s_ = 0; s_ < 3; ++s_)                                      \
            _Pragma("unroll")                                               \
            for (int n_ = 0; n_ < 4; ++n_)                                  \
                Bd[s_][n_] = *(const bf16x8*)(bb_ + s_ * 2048 + n_ * 512);  \
    } while (0)

#define LOADA(Ad, kk) do {                                                  \
        Ad[0][0] = *(const float4*)(ra0 + (kk) * 32);                       \
        Ad[0][1] = *(const float4*)(ra0 + (kk) * 32 + 4);                   \
        Ad[1][0] = *(const float4*)(ra1 + (kk) * 32);                       \
        Ad[1][1] = *(const float4*)(ra1 + (kk) * 32 + 4);                   \
    } while (0)

// per row-tile: split A into bf16^3, then 6 MFMA terms x 4 expert-frags,
// term-major / n-minor so dependent same-acc MFMAs are 4 issues apart.
#define COMPUTE(Bd, Ad) do {                                                \
        _Pragma("unroll")                                                   \
        for (int rt_ = 0; rt_ < 2; ++rt_) {                                 \
            float av_[8] = {Ad[rt_][0].x, Ad[rt_][0].y, Ad[rt_][0].z,       \
                            Ad[rt_][0].w, Ad[rt_][1].x, Ad[rt_][1].y,       \
                            Ad[rt_][1].z, Ad[rt_][1].w};                    \
            bf16x8 A1_, A2_, A3_;                                           \
            _Pragma("unroll")                                               \
            for (int j_ = 0; j_ < 8; ++j_) {                                \
                float x_  = av_[j_];                                        \
                __bf16 h1_ = (__bf16)x_;                                    \
                float r1_ = x_ - (float)h1_;                                \
                __bf16 h2_ = (__bf16)r1_;                                   \
                float r2_ = r1_ - (float)h2_;                               \
                A1_[j_] = h1_; A2_[j_] = h2_; A3_[j_] = (__bf16)r2_;        \
            }                                                               \
            _Pragma("unroll")                                               \
            for (int n_ = 0; n_ < 4; ++n_)                                  \
                accM[rt_][n_]  = __builtin_amdgcn_mfma_f32_16x16x32_bf16(A1_, Bd[0][n_], accM[rt_][n_], 0, 0, 0);  \
            _Pragma("unroll")                                               \
            for (int n_ = 0; n_ < 4; ++n_)                                  \
                accDL[rt_][n_] = __builtin_amdgcn_mfma_f32_16x16x32_bf16(A1_, Bd[1][n_], accDL[rt_][n_], 0, 0, 0); \
            _Pragma("unroll")                                               \
            for (int n_ = 0; n_ < 4; ++n_)                                  \
                accDL[rt_][n_] = __builtin_amdgcn_mfma_f32_16x16x32_bf16(A2_, Bd[0][n_], accDL[rt_][n_], 0, 0, 0); \
            _Pragma("unroll")                                               \
            for (int n_ = 0; n_ < 4; ++n_)                                  \
                accDL[rt_][n_] = __builtin_amdgcn_mfma_f32_16x16x32_bf16(A1_, Bd[2][n_], accDL[rt_][n_], 0, 0, 0); \
            _Pragma("unroll")                                               \
            for (int n_ = 0; n_ < 4; ++n_)                                  \
                accDL[rt_][n_] = __builtin_amdgcn_mfma_f32_16x16x32_bf16(A2_, Bd[1][n_], accDL[rt_][n_], 0, 0, 0); \
            _Pragma("unroll")                                               \
            for (int n_ = 0; n_ < 4; ++n_)                                  \
                accDL[rt_][n_] = __builtin_amdgcn_mfma_f32_16x16x32_bf16(A3_, Bd[0][n_], accDL[rt_][n_], 0, 0, 0); \
        }                                                                   \
    } while (0)

    // prologue: fill both pipeline slots (32 loads in flight)
    LOADB(B0, 0); LOADA(A0, 0);
    LOADB(B1, 1); LOADA(A1, 1);
    __builtin_amdgcn_sched_barrier(0);

    // steady state: compute(k) waits vmcnt(16) (k+1's loads stay in flight),
    // then issues k+2; fence stops the issues sinking past compute(k+1).
    for (int ks = 0; ks <= NK - 4; ks += 2) {
        COMPUTE(B0, A0);
        LOADB(B0, ks + 2); LOADA(A0, ks + 2);
        __builtin_amdgcn_sched_barrier(0);
        COMPUTE(B1, A1);
        LOADB(B1, ks + 3); LOADA(A1, ks + 3);
        __builtin_amdgcn_sched_barrier(0);
    }
    // epilogue: last two k-steps, no prefetch
    COMPUTE(B0, A0);
    COMPUTE(B1, A1);

#undef LOADB
#undef LOADA
#undef COMPUTE

    // C/D layout: col = lane&15, row = quad*4 + reg. Combine small-first,
    // one partial per K-quarter.
    #pragma unroll
    for (int rt = 0; rt < 2; ++rt)
        #pragma unroll
        for (int n = 0; n < 4; ++n) {
            int col = n * 16 + lrow;
            #pragma unroll
            for (int i = 0; i < 4; ++i)
                lg[wv][rt * 16 + quad * 4 + i][col] = accM[rt][n][i] + accDL[rt][n][i];
        }
    __syncthreads();   // the ONLY block-wide barrier

    // quarter-reduce + softmax + top-8; wave per row, lane = expert. T == 1.
    const float bcol = bias[lane];
    for (int rr = wv; rr < 32; rr += 4) {
        float logit = ((lg[0][rr][lane] + lg[1][rr][lane]) +
                       (lg[2][rr][lane] + lg[3][rr][lane])) + bcol;
        float mx = logit;
        #pragma unroll
        for (int s = 32; s >= 1; s >>= 1) mx = fmaxf(mx, __shfl_xor(mx, s));
        float ex = expf(logit - mx);
        float sm = ex;
        #pragma unroll
        for (int s = 32; s >= 1; s >>= 1) sm += __shfl_xor(sm, s);
        float soft = ex / sm;

        // top-8 on soft (monotone in logit); lowest-index tie-break = lax.top_k
        bool  sel    = false;
        float topsum = 0.0f;
        #pragma unroll
        for (int it = 0; it < TOPK; ++it) {
            float cand = sel ? -1.0f : soft;  // soft > 0 always
            float cm = cand;
            #pragma unroll
            for (int s = 32; s >= 1; s >>= 1) cm = fmaxf(cm, __shfl_xor(cm, s));
            unsigned long long ball = __ballot(cand == cm);
            int leader = __ffsll(ball) - 1;
            if (lane == leader) sel = true;
            topsum += cm;
        }
        float hard = sel ? soft / (topsum + 1e-9f) : 0.0f;

        size_t orow = (size_t)(row0 + rr) * E_DIM + lane;
        out[orow] = hard;
        out[(size_t)B_DIM * E_DIM + orow] = soft;
    }
}

extern "C" void kernel_launch(void* const* d_in, const int* in_sizes, int n_in,
                              void* d_out, int out_size, void* d_ws, size_t ws_size,
                              hipStream_t stream) {
    const float* r = (const float*)d_in[0];
    const float* W = (const float*)d_in[1];
    const float* b = (const float*)d_in[2];
    float* out = (float*)d_out;
    __bf16* P = (__bf16*)d_ws;   // 64 ksteps * 12 KB = 768 KB of ws

    w_prep<<<64, 256, 0, stream>>>(W, P);
    moe_gate<<<1024, 256, 0, stream>>>(r, P, b, out);
}